// Round 4
// baseline (501.577 us; speedup 1.0000x reference)
//
#include <hip/hip_runtime.h>
#include <stdint.h>

// Batched Viterbi decode: B=8192, T=512, K=12.
// 16 lanes per batch row (12 tag-lanes + 4 pad), 4 rows per wave.
// Per-step exchange: lane j writes its trellis value (ds_write_b32); each
// lane reads ONE 16B chunk of the group's 12-float row (ds_read_b128,
// chunk = min(lane&3,2)); the ordered 12-vector is then assembled with 12
// quad_perm DPP broadcasts (pure VALU, no LDS queue pressure, no latency).
// Value chain: 12 adds -> v_max3 tree -> +emit. Argmax off-chain via exact
// first-index equality scan. Emissions pipelined one 8-step block ahead in
// named regs. Backpointers packed 4 steps/dword: bpw[b][w][j], w in [0,128).
// Output = [scores: B floats][paths: B*T floats].

namespace {

constexpr int kB = 8192;
constexpr int kT = 512;
constexpr int kK = 12;
constexpr int kW = 128;

template <int CTRL>
__device__ __forceinline__ float dppb(float x) {
    // quad_perm broadcast: CTRL=0x00 -> quad lane0, 0x55 -> lane1, 0xAA -> lane2
    return __int_as_float(__builtin_amdgcn_update_dpp(
        0, __float_as_int(x), CTRL, 0xf, 0xf, true));
}

__global__ __launch_bounds__(256) void viterbi_fused(
    const float* __restrict__ logits,   // [B, T, K]
    const float* __restrict__ trans,    // [K, K]
    float* __restrict__ out,            // [B] scores + [B*T] paths
    uint32_t* __restrict__ bpw)         // [B, kW, kK]
{
    __shared__ __align__(64) float xch[16][16];   // 16 groups x 16 floats

    const int tid = blockIdx.x * 256 + threadIdx.x;
    const int b   = tid >> 4;
    const int j   = threadIdx.x & 15;
    const int g   = threadIdx.x >> 4;             // group within block
    const int jeff = (j < kK) ? j : (kK - 1);
    const int chunk = ((j & 3) == 3) ? 2 : (j & 3);

    float* __restrict__ xg = &xch[g][0];
    const float4* __restrict__ xgc = (const float4*)(xg + 4 * chunk);

    // transitions column jeff
    const float T0  = trans[0*kK+jeff],  T1  = trans[1*kK+jeff];
    const float T2  = trans[2*kK+jeff],  T3  = trans[3*kK+jeff];
    const float T4  = trans[4*kK+jeff],  T5  = trans[5*kK+jeff];
    const float T6  = trans[6*kK+jeff],  T7  = trans[7*kK+jeff];
    const float T8  = trans[8*kK+jeff],  T9  = trans[9*kK+jeff];
    const float T10 = trans[10*kK+jeff], T11 = trans[11*kK+jeff];

    const float* __restrict__ em = logits + (size_t)b * kT * kK + jeff;
    uint32_t* __restrict__ bpb = bpw + (size_t)b * kW * kK;

    float prev = em[0];

    // emissions for t = 1..8 in named regs
    float e0 = em[1*kK], e1 = em[2*kK], e2 = em[3*kK], e3 = em[4*kK];
    float e4 = em[5*kK], e5 = em[6*kK], e6 = em[7*kK], e7 = em[8*kK];

    uint32_t packed = 0;

#define EMLOAD(t) em[((t) < kT ? (t) : (kT - 1)) * kK]

#define EXCHANGE()                                                           \
    xg[j] = prev;                                                            \
    const float4 Q = *xgc;                                                   \
    const float p0 = dppb<0x00>(Q.x), p1 = dppb<0x00>(Q.y);                  \
    const float p2 = dppb<0x00>(Q.z), p3 = dppb<0x00>(Q.w);                  \
    const float p4 = dppb<0x55>(Q.x), p5 = dppb<0x55>(Q.y);                  \
    const float p6 = dppb<0x55>(Q.z), p7 = dppb<0x55>(Q.w);                  \
    const float p8 = dppb<0xAA>(Q.x), p9 = dppb<0xAA>(Q.y);                  \
    const float p10 = dppb<0xAA>(Q.z), p11 = dppb<0xAA>(Q.w)

#define STEP(K, WBASE, EMIT) do {                                            \
    EXCHANGE();                                                              \
    const float c0 = p0 + T0,   c1 = p1 + T1;                                \
    const float c2 = p2 + T2,   c3 = p3 + T3;                                \
    const float c4 = p4 + T4,   c5 = p5 + T5;                                \
    const float c6 = p6 + T6,   c7 = p7 + T7;                                \
    const float c8 = p8 + T8,   c9 = p9 + T9;                                \
    const float c10 = p10 + T10, c11 = p11 + T11;                            \
    const float m0 = fmaxf(fmaxf(c0, c1), c2);                               \
    const float m1 = fmaxf(fmaxf(c3, c4), c5);                               \
    const float m2 = fmaxf(fmaxf(c6, c7), c8);                               \
    const float m3 = fmaxf(fmaxf(c9, c10), c11);                             \
    const float best = fmaxf(fmaxf(m0, m1), fmaxf(m2, m3));                  \
    int bi = 11;                                                             \
    bi = (c10 == best) ? 10 : bi;  bi = (c9 == best) ? 9 : bi;               \
    bi = (c8  == best) ?  8 : bi;  bi = (c7 == best) ? 7 : bi;               \
    bi = (c6  == best) ?  6 : bi;  bi = (c5 == best) ? 5 : bi;               \
    bi = (c4  == best) ?  4 : bi;  bi = (c3 == best) ? 3 : bi;               \
    bi = (c2  == best) ?  2 : bi;  bi = (c1 == best) ? 1 : bi;               \
    bi = (c0  == best) ?  0 : bi;                                            \
    prev = best + (EMIT);                                                    \
    packed |= (uint32_t)bi << (8 * ((K) & 3));                               \
    if (((K) & 3) == 3) {                                                    \
        if (j < kK) bpb[(size_t)((WBASE) + ((K) >> 2)) * kK + j] = packed;   \
        packed = 0;                                                          \
    }                                                                        \
} while (0)

    // main: t = 1..504 in 63 guard-free blocks of 8
    for (int n = 0; n < 63; ++n) {
        const int tb = 8 * n + 1;
        const int w0 = 2 * n;
        // prefetch next block's emissions (t = tb+8 .. tb+15, clamped)
        const float f0 = EMLOAD(tb + 8),  f1 = EMLOAD(tb + 9);
        const float f2 = EMLOAD(tb + 10), f3 = EMLOAD(tb + 11);
        const float f4 = EMLOAD(tb + 12), f5 = EMLOAD(tb + 13);
        const float f6 = EMLOAD(tb + 14), f7 = EMLOAD(tb + 15);

        STEP(0, w0, e0); STEP(1, w0, e1); STEP(2, w0, e2); STEP(3, w0, e3);
        STEP(4, w0, e4); STEP(5, w0, e5); STEP(6, w0, e6); STEP(7, w0, e7);

        e0 = f0; e1 = f1; e2 = f2; e3 = f3;
        e4 = f4; e5 = f5; e6 = f6; e7 = f7;
    }

    // tail: t = 505..511 (e0..e6 hold em[505..511]); steps s = 504..510
    STEP(0, 126, e0); STEP(1, 126, e1); STEP(2, 126, e2); STEP(3, 126, e3);
    STEP(4, 126, e4); STEP(5, 126, e5); STEP(6, 126, e6);
    if (j < kK) bpb[(size_t)127 * kK + j] = packed;   // flush word 127 (3 bytes)

#undef STEP
#undef EMLOAD

    // final argmax over tags (first-index on ties)
    float best, v0, v1, v2, v3, v4, v5, v6, v7, v8, v9, v10, v11;
    {
        EXCHANGE();
        v0 = p0; v1 = p1; v2 = p2; v3 = p3; v4 = p4; v5 = p5;
        v6 = p6; v7 = p7; v8 = p8; v9 = p9; v10 = p10; v11 = p11;
        const float n0 = fmaxf(fmaxf(v0, v1), v2);
        const float n1 = fmaxf(fmaxf(v3, v4), v5);
        const float n2 = fmaxf(fmaxf(v6, v7), v8);
        const float n3 = fmaxf(fmaxf(v9, v10), v11);
        best = fmaxf(fmaxf(n0, n1), fmaxf(n2, n3));
    }
    int last = 11;
    last = (v10 == best) ? 10 : last;  last = (v9 == best) ? 9 : last;
    last = (v8  == best) ?  8 : last;  last = (v7 == best) ? 7 : last;
    last = (v6  == best) ?  6 : last;  last = (v5 == best) ? 5 : last;
    last = (v4  == best) ?  4 : last;  last = (v3 == best) ? 3 : last;
    last = (v2  == best) ?  2 : last;  last = (v1 == best) ? 1 : last;
    last = (v0  == best) ?  0 : last;

#undef EXCHANGE

    __syncthreads();  // drain backpointer stores before same-wave readback

    if (j == 0) {
        out[b] = best;
        float* __restrict__ paths = out + kB + (size_t)b * kT;
        paths[kT - 1] = (float)last;

        int tag = last;
        const uint4* __restrict__ r = (const uint4*)bpb;  // 3 uint4 per word
#pragma unroll 4
        for (int w = kW - 1; w >= 0; --w) {
            const uint4 q0 = r[w * 3 + 0];   // dwords j = 0..3
            const uint4 q1 = r[w * 3 + 1];   // j = 4..7
            const uint4 q2 = r[w * 3 + 2];   // j = 8..11
            const int smax = (w == kW - 1) ? 510 : (w * 4 + 3);
            for (int s = smax; s >= w * 4; --s) {
                const uint32_t ax = (tag & 8) ? q2.x : ((tag & 4) ? q1.x : q0.x);
                const uint32_t ay = (tag & 8) ? q2.y : ((tag & 4) ? q1.y : q0.y);
                const uint32_t az = (tag & 8) ? q2.z : ((tag & 4) ? q1.z : q0.z);
                const uint32_t aw = (tag & 8) ? q2.w : ((tag & 4) ? q1.w : q0.w);
                const uint32_t lo = (tag & 1) ? ay : ax;
                const uint32_t hi = (tag & 1) ? aw : az;
                const uint32_t dw = (tag & 2) ? hi : lo;
                tag = (int)((dw >> (8 * (s & 3))) & 0xFF);
                paths[s] = (float)tag;
            }
        }
    }
}

} // namespace

extern "C" void kernel_launch(void* const* d_in, const int* in_sizes, int n_in,
                              void* d_out, int out_size, void* d_ws, size_t ws_size,
                              hipStream_t stream) {
    const float* logits = (const float*)d_in[0];   // [8192, 512, 12] f32
    const float* trans  = (const float*)d_in[1];   // [12, 12] f32
    float* out = (float*)d_out;
    uint32_t* bpw = (uint32_t*)d_ws;               // 8192*128*12*4 = 50.3 MB

    const int threads = 256;
    const int blocks = (kB * 16) / threads;        // 512 blocks
    viterbi_fused<<<blocks, threads, 0, stream>>>(logits, trans, out, bpw);
}